// Round 6
// baseline (10435.501 us; speedup 1.0000x reference)
//
#include <hip/hip_runtime.h>
#include <math.h>

#define T_STEPS 2048
#define BATCH   32
#define IN_DIM  512
#define H_DIM   512
#define G4      2048
#define NWG     16
#define NTHR    512
#define GLS     132      // gates LDS row stride (floats), padded

typedef __attribute__((ext_vector_type(8))) short short8;
typedef __attribute__((ext_vector_type(4))) float f32x4;
typedef __attribute__((ext_vector_type(4))) unsigned u32x4;

__device__ inline unsigned short f2bf(float f) {
    unsigned u = __builtin_bit_cast(unsigned, f);
    unsigned r = (u + 0x7FFFu + ((u >> 16) & 1u)) >> 16;
    return (unsigned short)r;
}
__device__ inline unsigned pack2(float a, float b) {
    return (unsigned)f2bf(a) | ((unsigned)f2bf(b) << 16);
}
__device__ inline float sigm(float v) { return 1.f / (1.f + expf(-v)); }

// 4 parallel IC-coherent 16B loads + drain (round-4 proven)
__device__ inline void ld4x_ic(const void* p0, const void* p1,
                               const void* p2, const void* p3,
                               u32x4& v0, u32x4& v1, u32x4& v2, u32x4& v3) {
    asm volatile(
        "global_load_dwordx4 %0, %4, off sc1\n\t"
        "global_load_dwordx4 %1, %5, off sc1\n\t"
        "global_load_dwordx4 %2, %6, off sc1\n\t"
        "global_load_dwordx4 %3, %7, off sc1\n\t"
        "s_waitcnt vmcnt(0)"
        : "=&v"(v0), "=&v"(v1), "=&v"(v2), "=&v"(v3)
        : "v"(p0), "v"(p1), "v"(p2), "v"(p3) : "memory");
}

// ---------------------------------------------------------------------------
// W [1024][2048] fp32 -> Wt [2048][1024] bf16 (transposed; k<512 = x-part)
// ---------------------------------------------------------------------------
__global__ __launch_bounds__(256) void wt_kernel(const float* __restrict__ W,
                                                 unsigned short* __restrict__ Wt) {
    __shared__ unsigned short tile[32][33];
    const int n0 = blockIdx.x << 5, k0 = blockIdx.y << 5;
    const int tx = threadIdx.x & 31, ty = threadIdx.x >> 5;
    #pragma unroll
    for (int r = 0; r < 32; r += 8)
        tile[ty + r][tx] = f2bf(W[(size_t)(k0 + ty + r) * G4 + n0 + tx]);
    __syncthreads();
    #pragma unroll
    for (int r = 0; r < 32; r += 8)
        Wt[(size_t)(n0 + ty + r) * 1024 + k0 + tx] = tile[tx][ty + r];
}

__global__ void init_h(const float* __restrict__ h0, unsigned short* __restrict__ hb) {
    int i = blockIdx.x * 256 + threadIdx.x;   // 16384 total
    hb[i] = f2bf(h0[i]);
}

// x fp32 -> bf16 (33.5M elems, 8/thread)
__global__ __launch_bounds__(256) void xb_kernel(const float* __restrict__ x,
                                                 unsigned short* __restrict__ xb) {
    const size_t i = ((size_t)blockIdx.x * 256 + threadIdx.x) * 8;
    const float4 a = *(const float4*)(x + i);
    const float4 b = *(const float4*)(x + i + 4);
    u32x4 v;
    v.x = pack2(a.x, a.y); v.y = pack2(a.z, a.w);
    v.z = pack2(b.x, b.y); v.w = pack2(b.z, b.w);
    *(u32x4*)(xb + i) = v;
}

// ---------------------------------------------------------------------------
// Fused persistent scan: 16 WGs x 512 thr (8 waves). WG g owns hidden cols
// [g*32,(g+1)*32) -> 128 gate cols. W_h AND W_x fragments in VGPRs (128 regs);
// x(t+1) double-buffered through LDS; bias in acc init; c in registers.
// Sync = round-4 proven protocol: vmcnt(0) drain -> atomicAdd (IC) ->
// sc1-load poll -> sc1 h staging. One barrier per step.
// ---------------------------------------------------------------------------
__global__ __launch_bounds__(NTHR, 1) void lstm_scan(
        const unsigned short* __restrict__ Wt,   // [2048][1024]
        const unsigned short* __restrict__ xb,   // [2048][32][512] bf16
        const float* __restrict__ bias,          // [2048]
        const float* __restrict__ c0,            // [32][512]
        unsigned short* __restrict__ hbuf,       // [2][32][512] bf16, [0] init'd
        float* __restrict__ outs,                // [2048][32][512]
        float* __restrict__ hf, float* __restrict__ cf,
        unsigned int* __restrict__ bar) {
    __shared__ char LDS_[65536];
    char* Hl = LDS_;            // h: 32 rows x 1KB, swizzled; gates alias after MFMA
    char* Xl = LDS_ + 32768;    // x(t): same layout

    const int g = blockIdx.x;
    const int tid = threadIdx.x;
    const int w = tid >> 6, l = tid & 63;

    // --- W fragments: wave w -> global gate cols gc (16 cols/wave)
    const int gc = ((w >> 1) << 9) + (g << 5) + ((w & 1) << 4) + (l & 15);
    const int ksub = (l >> 4) << 3;
    short8 wfh[16], wfx[16];
    #pragma unroll
    for (int kc = 0; kc < 16; ++kc) {
        wfh[kc] = *(const short8*)(Wt + (size_t)gc * 1024 + 512 + kc * 32 + ksub);
        wfx[kc] = *(const short8*)(Wt + (size_t)gc * 1024 +       kc * 32 + ksub);
    }
    const float bb = bias[gc];

    // --- update-phase mapping: thread -> (b, even col pair)
    const int b   = tid >> 4;
    const int hcp = (tid & 15) << 1;
    const int col = (g << 5) + hcp;
    float2 cv = *(const float2*)(c0 + (b << 9) + col);

    const int arow0 = l & 15, arow1 = (l & 15) + 16;
    const int kbyte = (l >> 4) << 4;
    const int swz0 = (arow0 & 7) << 4, swz1 = (arow1 & 7) << 4;
    const int lcw = (w << 4) + (l & 15);

    // --- pre-stage x(0) -> Xl (plain loads) and h(0) -> Hl (IC loads)
    {
        const u32x4* xsrc = (const u32x4*)xb;
        u32x4 p0 = xsrc[(w << 6) + l], p1 = xsrc[(w << 6) + l + 512];
        u32x4 p2 = xsrc[(w << 6) + l + 1024], p3 = xsrc[(w << 6) + l + 1536];
        char* xd = Xl + w * 1024 + ((l << 4) ^ (w << 4));
        *(u32x4*)xd = p0; *(u32x4*)(xd + 8192) = p1;
        *(u32x4*)(xd + 16384) = p2; *(u32x4*)(xd + 24576) = p3;

        const unsigned short* hp0 = hbuf + (w << 9) + (l << 3);
        u32x4 v0, v1, v2, v3;
        ld4x_ic(hp0, hp0 + 4096, hp0 + 8192, hp0 + 12288, v0, v1, v2, v3);
        char* hd = Hl + w * 1024 + ((l << 4) ^ (w << 4));
        *(u32x4*)hd = v0; *(u32x4*)(hd + 8192) = v1;
        *(u32x4*)(hd + 16384) = v2; *(u32x4*)(hd + 24576) = v3;
    }
    __syncthreads();

    for (int gt = 0; gt < T_STEPS; ++gt) {
        // 1. prefetch x(gt+1) into regs (independent of recurrence)
        const int gtn = (gt < T_STEPS - 1) ? gt + 1 : gt;
        const u32x4* xsrc = (const u32x4*)(xb + ((size_t)gtn << 14));
        const u32x4 px0 = xsrc[(w << 6) + l];
        const u32x4 px1 = xsrc[(w << 6) + l + 512];
        const u32x4 px2 = xsrc[(w << 6) + l + 1024];
        const u32x4 px3 = xsrc[(w << 6) + l + 1536];

        // 2. MFMA: gates = bias + h@Wh + x@Wx  (4 independent chains)
        f32x4 ah0 = {bb, bb, bb, bb}, ah1 = {bb, bb, bb, bb};
        f32x4 ax0 = {0.f, 0.f, 0.f, 0.f}, ax1 = {0.f, 0.f, 0.f, 0.f};
        #pragma unroll
        for (int kc = 0; kc < 16; ++kc) {
            const int kb2 = kc * 64 + kbyte;
            short8 ha0 = *(const short8*)(Hl + arow0 * 1024 + (kb2 ^ swz0));
            short8 ha1 = *(const short8*)(Hl + arow1 * 1024 + (kb2 ^ swz1));
            short8 qa0 = *(const short8*)(Xl + arow0 * 1024 + (kb2 ^ swz0));
            short8 qa1 = *(const short8*)(Xl + arow1 * 1024 + (kb2 ^ swz1));
            ah0 = __builtin_amdgcn_mfma_f32_16x16x32_bf16(ha0, wfh[kc], ah0, 0, 0, 0);
            ax0 = __builtin_amdgcn_mfma_f32_16x16x32_bf16(qa0, wfx[kc], ax0, 0, 0, 0);
            ah1 = __builtin_amdgcn_mfma_f32_16x16x32_bf16(ha1, wfh[kc], ah1, 0, 0, 0);
            ax1 = __builtin_amdgcn_mfma_f32_16x16x32_bf16(qa1, wfx[kc], ax1, 0, 0, 0);
        }
        const f32x4 acc0 = ah0 + ax0;
        const f32x4 acc1 = ah1 + ax1;
        __syncthreads();                       // Hl/Xl reads done

        // 3. gates -> LDS (alias Hl region); x(gt+1) -> Xl
        float* Gl = (float*)Hl;
        #pragma unroll
        for (int ri = 0; ri < 4; ++ri) {
            const int br = ((l >> 4) << 2) + ri;
            Gl[br * GLS + lcw] = acc0[ri];
            Gl[(br + 16) * GLS + lcw] = acc1[ri];
        }
        {
            char* xd = Xl + w * 1024 + ((l << 4) ^ (w << 4));
            *(u32x4*)xd = px0; *(u32x4*)(xd + 8192) = px1;
            *(u32x4*)(xd + 16384) = px2; *(u32x4*)(xd + 24576) = px3;
        }
        __syncthreads();                       // gates visible

        // 4. elementwise update: (b, cols hcp, hcp+1)
        const float* grow = Gl + b * GLS + hcp;
        const float f0 = sigm(grow[0]),   f1 = sigm(grow[1]);
        const float i0 = sigm(grow[32]),  i1 = sigm(grow[33]);
        const float g0 = tanhf(grow[64]), g1 = tanhf(grow[65]);
        const float o0 = sigm(grow[96]),  o1 = sigm(grow[97]);
        cv.x = f0 * cv.x + i0 * g0;
        cv.y = f1 * cv.y + i1 * g1;
        const float hn0 = o0 * tanhf(cv.x);
        const float hn1 = o1 * tanhf(cv.y);

        // 5. stores: outs (plain), h for next step (IC-coherent)
        *(float2*)(outs + ((size_t)gt << 14) + (b << 9) + col) = make_float2(hn0, hn1);
        {
            unsigned* hdst = (unsigned*)hbuf + (((gt + 1) & 1) << 13) + (b << 8) + (col >> 1);
            const unsigned pk = pack2(hn0, hn1);
            asm volatile("global_store_dword %0, %1, off sc1" :: "v"(hdst), "v"(pk) : "memory");
        }
        if (gt == T_STEPS - 1) {
            *(float2*)(hf + (b << 9) + col) = make_float2(hn0, hn1);
            *(float2*)(cf + (b << 9) + col) = make_float2(cv.x, cv.y);
            break;                              // no final barrier needed
        }

        // 6. grid barrier (round-4 proven): drain h stores, atomic, sc1 poll
        asm volatile("s_waitcnt vmcnt(0)" ::: "memory");
        __syncthreads();
        if (tid == 0) {
            atomicAdd(bar, 1u);
            const unsigned tgt = (unsigned)(gt + 1) * NWG;
            for (;;) {
                unsigned vb;
                asm volatile("global_load_dword %0, %1, off sc1\n\ts_waitcnt vmcnt(0)"
                             : "=v"(vb) : "v"(bar) : "memory");
                if (vb >= tgt) break;
                __builtin_amdgcn_s_sleep(1);
            }
        }
        __syncthreads();

        // 7. stage h(gt+1) -> Hl (IC-coherent)
        {
            const unsigned short* hsrc = hbuf + (((gt + 1) & 1) << 14) + (w << 9) + (l << 3);
            u32x4 v0, v1, v2, v3;
            ld4x_ic(hsrc, hsrc + 4096, hsrc + 8192, hsrc + 12288, v0, v1, v2, v3);
            char* hd = Hl + w * 1024 + ((l << 4) ^ (w << 4));
            *(u32x4*)hd = v0; *(u32x4*)(hd + 8192) = v1;
            *(u32x4*)(hd + 16384) = v2; *(u32x4*)(hd + 24576) = v3;
        }
        __syncthreads();                       // Hl ready
    }
}

// ---------------------------------------------------------------------------
// Minimal fallback (tiny ws): 2048 step launches, fp32, x folded in.
// ---------------------------------------------------------------------------
__global__ __launch_bounds__(256) void lstm_step(const float* __restrict__ x_t,
                                                 const float* __restrict__ h_prev,
                                                 const float* __restrict__ W,
                                                 const float* __restrict__ bias,
                                                 const float* __restrict__ c_in,
                                                 float* __restrict__ c_out,
                                                 float* __restrict__ h_out,
                                                 float* __restrict__ hf,
                                                 float* __restrict__ cf, int last) {
    const int tid = threadIdx.x;
    const int hcc = tid & 7, b = tid >> 3;
    const int col = blockIdx.x * 8 + hcc;
    float a0 = bias[col], a1 = bias[col + 512], a2 = bias[col + 1024], a3 = bias[col + 1536];
    const float* xr = x_t + (size_t)b * IN_DIM;
    const float* hr = h_prev + (size_t)b * H_DIM;
    for (int k = 0; k < IN_DIM; ++k) {
        const float v = xr[k];
        const float* wk = &W[(size_t)k * G4 + col];
        a0 += v * wk[0]; a1 += v * wk[512]; a2 += v * wk[1024]; a3 += v * wk[1536];
    }
    for (int k = 0; k < H_DIM; ++k) {
        const float v = hr[k];
        const float* wk = &W[(size_t)(512 + k) * G4 + col];
        a0 += v * wk[0]; a1 += v * wk[512]; a2 += v * wk[1024]; a3 += v * wk[1536];
    }
    const float cn = sigm(a0) * c_in[(size_t)b * H_DIM + col] + sigm(a1) * tanhf(a2);
    const float hn = sigm(a3) * tanhf(cn);
    c_out[(size_t)b * H_DIM + col] = cn;
    h_out[(size_t)b * H_DIM + col] = hn;
    if (last) { hf[(size_t)b * H_DIM + col] = hn; cf[(size_t)b * H_DIM + col] = cn; }
}

extern "C" void kernel_launch(void* const* d_in, const int* in_sizes, int n_in,
                              void* d_out, int out_size, void* d_ws, size_t ws_size,
                              hipStream_t stream) {
    const float* x    = (const float*)d_in[0];
    const float* h0   = (const float*)d_in[1];
    const float* c0   = (const float*)d_in[2];
    const float* W    = (const float*)d_in[3];
    const float* bias = (const float*)d_in[4];

    float* outs = (float*)d_out;
    float* hf   = outs + (size_t)T_STEPS * BATCH * H_DIM;
    float* cf   = hf + BATCH * H_DIM;

    const size_t OFF_WT = 67108864ull;            // xb: 64 MB @ 0
    const size_t OFF_HB = OFF_WT + 4194304ull;    // Wt: 4 MB
    const size_t OFF_BA = OFF_HB + 65536ull;      // hbuf: 64 KB
    const size_t NEED   = OFF_BA + 4096ull;       // ~68.2 MB

    if (ws_size >= NEED) {
        unsigned short* xb = (unsigned short*)d_ws;
        unsigned short* Wt = (unsigned short*)((char*)d_ws + OFF_WT);
        unsigned short* hb = (unsigned short*)((char*)d_ws + OFF_HB);
        unsigned int* bar  = (unsigned int*)((char*)d_ws + OFF_BA);

        hipMemsetAsync(bar, 0, 256, stream);
        wt_kernel<<<dim3(64, 32), 256, 0, stream>>>(W, Wt);
        init_h<<<64, 256, 0, stream>>>(h0, hb);
        xb_kernel<<<16384, 256, 0, stream>>>(x, xb);
        lstm_scan<<<NWG, NTHR, 0, stream>>>(Wt, xb, bias, c0, hb, outs, hf, cf, bar);
    } else {
        float* c_ws = (float*)d_ws;
        for (int t = 0; t < T_STEPS; ++t) {
            const float* hp = t ? outs + (size_t)(t - 1) * BATCH * H_DIM : h0;
            const float* ci = t ? c_ws : c0;
            lstm_step<<<64, 256, 0, stream>>>(x + (size_t)t * BATCH * IN_DIM,
                                              hp, W, bias, ci, c_ws,
                                              outs + (size_t)t * BATCH * H_DIM,
                                              hf, cf, (t == T_STEPS - 1) ? 1 : 0);
        }
    }
}